// Round 4
// baseline (6999.265 us; speedup 1.0000x reference)
//
#include <hip/hip_runtime.h>
#include <hip/hip_bf16.h>

typedef __attribute__((ext_vector_type(8))) short short8;
typedef __attribute__((ext_vector_type(4))) float floatx4;

#define BB 2048   // batch
#define SS 24     // seq len (src and tgt)
#define HH 1024   // hidden
#define VV 37     // vocab
#define EE 256    // embed
#define G4H 4096  // 4*H gates

__device__ __forceinline__ unsigned short f2bf(float f) {
    union { float f; unsigned u; } x; x.f = f;
    unsigned r = x.u + 0x7FFF + ((x.u >> 16) & 1);   // RNE
    return (unsigned short)(r >> 16);
}
__device__ __forceinline__ float bf2f(unsigned short s) {
    union { unsigned u; float f; } x; x.u = ((unsigned)s) << 16; return x.f;
}
__device__ __forceinline__ float sigm(float x) {
    x = fminf(fmaxf(x, -15.f), 15.f);
    return 1.f / (1.f + __expf(-x));
}
__device__ __forceinline__ float tanh_(float x) {
    x = fminf(fmaxf(x, -15.f), 15.f);
    float e = __expf(2.f * x);
    return (e - 1.f) / (e + 1.f);
}

// async global->LDS DMA, 16B/lane; LDS dest = wave-uniform base + lane*16 [m97/m104]
typedef const __attribute__((address_space(1))) void* gas_t;
typedef __attribute__((address_space(3))) void* las_t;
__device__ __forceinline__ void gl_lds16(const void* g, void* l) {
    __builtin_amdgcn_global_load_lds((gas_t)g, (las_t)l, 16, 0, 0);
}

// ---------------- fp32 -> bf16 plain conversion (fcW, emb) ----------------
__global__ __launch_bounds__(256)
void cvt_f2b_kernel(const float* __restrict__ s, unsigned short* __restrict__ d, int n4) {
    int i = blockIdx.x * 256 + threadIdx.x;
    if (i >= n4) return;
    float4 v = reinterpret_cast<const float4*>(s)[i];
    ushort4 o;
    o.x = f2bf(v.x); o.y = f2bf(v.y); o.z = f2bf(v.z); o.w = f2bf(v.w);
    reinterpret_cast<ushort4*>(d)[i] = o;
}

// ------- fp32 -> bf16 with gate interleave: out row u*4+g <- in row g*1024+u -------
__global__ __launch_bounds__(256)
void cvt_perm_kernel(const float* __restrict__ s, unsigned short* __restrict__ d, int kqshift) {
    int i = blockIdx.x * 256 + threadIdx.x;     // over 4096 * K/4 float4 groups
    int kq = 1 << kqshift;
    int r  = i >> kqshift;                      // out row 0..4095
    int kk = i & (kq - 1);
    int u = r >> 2, g = r & 3;
    float4 v = reinterpret_cast<const float4*>(s)[(size_t)((g << 10) + u) * kq + kk];
    ushort4 o;
    o.x = f2bf(v.x); o.y = f2bf(v.y); o.z = f2bf(v.z); o.w = f2bf(v.w);
    reinterpret_cast<ushort4*>(d)[(size_t)i] = o;
}

// ---------------- zero init (h0a,h1a bf16 + c0,c1 fp32 region, 24 MiB) ----------------
__global__ __launch_bounds__(256) void zero16_kernel(uint4* __restrict__ p) {
    uint4 z; z.x = 0; z.y = 0; z.z = 0; z.w = 0;
    p[(size_t)blockIdx.x * 256 + threadIdx.x] = z;
}

// ---------------- token matrix [2,S,B] ----------------
__global__ __launch_bounds__(256)
void tok_kernel(const int* __restrict__ src, const int* __restrict__ tgt, int* __restrict__ toks) {
    int idx = blockIdx.x * 256 + threadIdx.x;   // 2*24*2048
    int b  = idx & 2047;
    int st = idx >> 11;
    int tok;
    if (st < SS) tok = src[b * SS + st];
    else { int t = st - SS; tok = (t == 0) ? 1 : tgt[b * SS + (t - 1)]; }
    toks[idx] = tok;
}

// ---------------- per-layer bias sums, gate-interleaved ----------------
__global__ __launch_bounds__(256) void bias_sum_kernel(
        const float* e0i, const float* e0h, const float* e1i, const float* e1h,
        const float* d0i, const float* d0h, const float* d1i, const float* d1h,
        float* __restrict__ out) {
    int idx = blockIdx.x * 256 + threadIdx.x;   // 4*4096
    int layer = idx >> 12, jj = idx & 4095;
    int u = jj >> 2, g = jj & 3;
    int src_j = (g << 10) + u;
    const float* pi; const float* ph;
    switch (layer) {
        case 0:  pi = e0i; ph = e0h; break;
        case 1:  pi = e1i; ph = e1h; break;
        case 2:  pi = d0i; ph = d0h; break;
        default: pi = d1i; ph = d1h; break;
    }
    out[idx] = pi[src_j] + ph[src_j];
}

// ---------------- merged fused LSTM step ----------------
// Two independent parts in one dispatch (blockIdx.z): z=0 -> layer1 step t,
// z=1 -> layer0 step t+1. Each part: gates = Wh @ h^T + Wx @ x^T + bias (all
// weight rows gate-interleaved: row 4u+g), then in-register cell:
// c = sig(f)*c + sig(i)*tanh(g); h = sig(o)*tanh(c).
// A-operand = weights (M = gate dims), B-operand = batch (N). With C/D layout
// col=lane&15, row=quad*4+reg [m89], each lane's acc[i][j] = the 4 gates of one
// (unit, batch) pair -> no LDS transpose, epilogue fully in-register.
// 128x128 tile, BK=64, 4 waves x (4x4) mfma_f32_16x16x32_bf16, global_load_lds.
__global__ __launch_bounds__(256, 4)
void lstm_merged(int v0, const unsigned short* __restrict__ Wh0, const unsigned short* __restrict__ SA0,
                 const unsigned short* __restrict__ Wx0, const unsigned short* __restrict__ SB0,
                 int Kx0, const int* __restrict__ tok0, const float4* __restrict__ b40,
                 float* __restrict__ cc0, unsigned short* __restrict__ ho0,
                 int v1, const unsigned short* __restrict__ Wh1, const unsigned short* __restrict__ SA1,
                 const unsigned short* __restrict__ Wx1, const unsigned short* __restrict__ SB1,
                 int Kx1, const int* __restrict__ tok1, const float4* __restrict__ b41,
                 float* __restrict__ cc1, unsigned short* __restrict__ ho1) {
    const unsigned short *Wh, *SA, *Wx, *SB; int Kx; const int* tok;
    const float4* b4; float* c; unsigned short* hout;
    if (blockIdx.z == 0) {
        if (!v0) return;
        Wh = Wh0; SA = SA0; Wx = Wx0; SB = SB0; Kx = Kx0; tok = tok0; b4 = b40; c = cc0; hout = ho0;
    } else {
        if (!v1) return;
        Wh = Wh1; SA = SA1; Wx = Wx1; SB = SB1; Kx = Kx1; tok = tok1; b4 = b41; c = cc1; hout = ho1;
    }

    // As: W tiles (gate dims), Bs: state tiles (batch). 16 subtiles x 512 shorts each.
    __shared__ __align__(16) unsigned short As[8192];
    __shared__ __align__(16) unsigned short Bs[8192];

    const int tid  = threadIdx.x;
    const int lane = tid & 63;
    const int wave = tid >> 6;
    const int wm = wave >> 1, wn = wave & 1;
    const int m0 = blockIdx.x * 128;   // gate-dim base (0..4095)
    const int n0 = blockIdx.y * 128;   // batch base   (0..2047)

    floatx4 acc[4][4];
#pragma unroll
    for (int i = 0; i < 4; ++i)
#pragma unroll
        for (int j = 0; j < 4; ++j)
            acc[i][j] = (floatx4){0.f, 0.f, 0.f, 0.f};

    const int r16  = lane & 15;
    const int koff = (lane >> 4) << 3;
    const int t0 = wave, t1 = wave + 4;

#pragma unroll
    for (int seg = 0; seg < 2; ++seg) {
        const unsigned short* A = seg ? Wx : Wh;   // weights (A-operand)
        const unsigned short* B = seg ? SB : SA;   // batch state / x (B-operand)
        const int K = seg ? Kx : HH;
        const size_t a0 = (size_t)(m0 + t0 * 16 + r16) * K + koff;
        const size_t a1 = (size_t)(m0 + t1 * 16 + r16) * K + koff;
        size_t b0, b1;
        if (seg == 1 && tok != nullptr) {
            b0 = (size_t)tok[n0 + t0 * 16 + r16] * K + koff;
            b1 = (size_t)tok[n0 + t1 * 16 + r16] * K + koff;
        } else {
            b0 = (size_t)(n0 + t0 * 16 + r16) * K + koff;
            b1 = (size_t)(n0 + t1 * 16 + r16) * K + koff;
        }
        for (int kc = 0; kc < K; kc += 64) {
            gl_lds16(A + a0 + kc,      As + ((t0 * 2 + 0) << 9));
            gl_lds16(A + a0 + kc + 32, As + ((t0 * 2 + 1) << 9));
            gl_lds16(A + a1 + kc,      As + ((t1 * 2 + 0) << 9));
            gl_lds16(A + a1 + kc + 32, As + ((t1 * 2 + 1) << 9));
            gl_lds16(B + b0 + kc,      Bs + ((t0 * 2 + 0) << 9));
            gl_lds16(B + b0 + kc + 32, Bs + ((t0 * 2 + 1) << 9));
            gl_lds16(B + b1 + kc,      Bs + ((t1 * 2 + 0) << 9));
            gl_lds16(B + b1 + kc + 32, Bs + ((t1 * 2 + 1) << 9));
            __syncthreads();
#pragma unroll
            for (int h = 0; h < 2; ++h) {
                short8 af[4], bfr[4];
#pragma unroll
                for (int i = 0; i < 4; ++i) {
                    af[i]  = *reinterpret_cast<const short8*>(As + ((((wm * 4 + i) * 2 + h) << 9) + (lane << 3)));
                    bfr[i] = *reinterpret_cast<const short8*>(Bs + ((((wn * 4 + i) * 2 + h) << 9) + (lane << 3)));
                }
#pragma unroll
                for (int i = 0; i < 4; ++i)
#pragma unroll
                    for (int j = 0; j < 4; ++j)
                        acc[i][j] = __builtin_amdgcn_mfma_f32_16x16x32_bf16(af[i], bfr[j], acc[i][j], 0, 0, 0);
            }
            __syncthreads();
        }
    }

    // ---- in-register LSTM cell epilogue ----
    // lane: r=lane&15 -> batch col offset; q=lane>>4 -> unit sub-index.
    // acc[i][j] = (i,f,g,o) of unit (m0>>2)+wm*16+i*4+q, batch n0+wn*64+j*16+r.
    const int r = lane & 15, q = lane >> 4;
    const int ubase = (m0 >> 2) + wm * 16 + q;
#pragma unroll
    for (int i = 0; i < 4; ++i) {
        const int unit = ubase + i * 4;
        const float4 bv = b4[unit];
#pragma unroll
        for (int j = 0; j < 4; ++j) {
            const int batch = n0 + wn * 64 + j * 16 + r;
            float iv = sigm(acc[i][j][0] + bv.x);
            float fv = sigm(acc[i][j][1] + bv.y);
            float gv = tanh_(acc[i][j][2] + bv.z);
            float ov = sigm(acc[i][j][3] + bv.w);
            const size_t ci = (size_t)batch * HH + unit;
            float cn = fv * c[ci] + iv * gv;
            c[ci] = cn;
            hout[ci] = f2bf(ov * tanh_(cn));
        }
    }
}

// ---------------- FC head, one timestep ----------------
__global__ __launch_bounds__(256)
void fc_step_kernel(const unsigned short* __restrict__ h1, const unsigned short* __restrict__ fcW,
                    const float* __restrict__ fcb,
                    float* __restrict__ out, int t) {
    int b    = (blockIdx.x * 256 + threadIdx.x) >> 6;
    int lane = threadIdx.x & 63;
    if (lane >= VV) return;
    const unsigned short* hrow = h1 + (size_t)b * HH;
    const unsigned short* wrow = fcW + (size_t)lane * HH;
    float acc = fcb[lane];
#pragma unroll 4
    for (int k8 = 0; k8 < HH / 8; ++k8) {
        short8 hv = *reinterpret_cast<const short8*>(hrow + k8 * 8);
        short8 wv = *reinterpret_cast<const short8*>(wrow + k8 * 8);
#pragma unroll
        for (int uu = 0; uu < 8; ++uu)
            acc += bf2f((unsigned short)hv[uu]) * bf2f((unsigned short)wv[uu]);
    }
    out[(size_t)b * (SS * VV) + t * VV + lane] = acc;
}

extern "C" void kernel_launch(void* const* d_in, const int* in_sizes, int n_in,
                              void* d_out, int out_size, void* d_ws, size_t ws_size,
                              hipStream_t stream) {
    const int*   src    = (const int*)d_in[0];
    const int*   tgt    = (const int*)d_in[1];
    const float* emb    = (const float*)d_in[2];
    const float* eW_ih0 = (const float*)d_in[3];
    const float* eW_hh0 = (const float*)d_in[4];
    const float* eb_ih0 = (const float*)d_in[5];
    const float* eb_hh0 = (const float*)d_in[6];
    const float* eW_ih1 = (const float*)d_in[7];
    const float* eW_hh1 = (const float*)d_in[8];
    const float* eb_ih1 = (const float*)d_in[9];
    const float* eb_hh1 = (const float*)d_in[10];
    const float* dW_ih0 = (const float*)d_in[11];
    const float* dW_hh0 = (const float*)d_in[12];
    const float* db_ih0 = (const float*)d_in[13];
    const float* db_hh0 = (const float*)d_in[14];
    const float* dW_ih1 = (const float*)d_in[15];
    const float* dW_hh1 = (const float*)d_in[16];
    const float* db_ih1 = (const float*)d_in[17];
    const float* db_hh1 = (const float*)d_in[18];
    const float* fcW    = (const float*)d_in[19];
    const float* fcb    = (const float*)d_in[20];
    float* out = (float*)d_out;

    // ---- workspace layout ----
    char* w = (char*)d_ws;
    size_t off = 0;
    auto walloc = [&](size_t bytes) { void* p = w + off; off += (bytes + 255) & ~(size_t)255; return p; };
    unsigned short* bW[8];
    const float* srcW[8] = {eW_ih0, eW_hh0, eW_ih1, eW_hh1, dW_ih0, dW_hh0, dW_ih1, dW_hh1};
    const int     szW[8] = {G4H*EE, G4H*HH, G4H*HH, G4H*HH, G4H*EE, G4H*HH, G4H*HH, G4H*HH};
    for (int i = 0; i < 8; ++i) bW[i] = (unsigned short*)walloc((size_t)szW[i] * 2);
    unsigned short* bfcW = (unsigned short*)walloc((size_t)VV * HH * 2);
    unsigned short* bemb = (unsigned short*)walloc((size_t)VV * EE * 2);
    // zero region: h0a, h1a (bf16) + c0, c1 (fp32) — contiguous 24 MiB
    unsigned short* h0a = (unsigned short*)walloc((size_t)BB * HH * 2);
    unsigned short* h1a = (unsigned short*)walloc((size_t)BB * HH * 2);
    float* c0 = (float*)walloc((size_t)BB * HH * 4);
    float* c1 = (float*)walloc((size_t)BB * HH * 4);
    unsigned short* h0b = (unsigned short*)walloc((size_t)BB * HH * 2);
    unsigned short* h1b = (unsigned short*)walloc((size_t)BB * HH * 2);
    float* bsum = (float*)walloc((size_t)4 * G4H * 4);
    int*   toks = (int*)walloc((size_t)2 * SS * BB * 4);

    unsigned short* h0buf[2] = {h0a, h0b};
    unsigned short* h1buf[2] = {h1a, h1b};
    const float4* b4 = (const float4*)bsum;   // [4 layers][1024 units] of (i,f,g,o)

    // ---- setup ----
    for (int i = 0; i < 8; ++i) {
        int kqshift = (szW[i] == G4H * EE) ? 6 : 8;     // K/4 = 64 or 256
        cvt_perm_kernel<<<szW[i] / 4 / 256, 256, 0, stream>>>(srcW[i], bW[i], kqshift);
    }
    cvt_f2b_kernel<<<(VV * HH / 4 + 255) / 256, 256, 0, stream>>>(fcW, bfcW, VV * HH / 4);
    cvt_f2b_kernel<<<(VV * EE / 4 + 255) / 256, 256, 0, stream>>>(emb, bemb, VV * EE / 4);
    zero16_kernel<<<6144, 256, 0, stream>>>((uint4*)h0a);
    bias_sum_kernel<<<64, 256, 0, stream>>>(eb_ih0, eb_hh0, eb_ih1, eb_hh1,
                                            db_ih0, db_hh0, db_ih1, db_hh1, bsum);
    tok_kernel<<<384, 256, 0, stream>>>(src, tgt, toks);

    dim3 ggrid(G4H / 128, BB / 128, 2);   // (32, 16, 2) = 1024 blocks

    // ---- prologue: layer0 step 0 only (part z=1) ----
    lstm_merged<<<ggrid, 256, 0, stream>>>(
        0, nullptr, nullptr, nullptr, nullptr, 0, nullptr, nullptr, nullptr, nullptr,
        1, bW[1], h0buf[0], bW[0], bemb, EE, toks, b4 + 0 * 1024, c0, h0buf[1]);

    // ---- main pipeline: dispatch d = layer1 step d + layer0 step d+1 ----
    for (int d = 0; d < 48; ++d) {
        const unsigned short* h0cur = h0buf[1 ^ (d & 1)];
        unsigned short*       h0nxt = h0buf[d & 1];
        const unsigned short* h1in  = h1buf[d & 1];
        unsigned short*       h1out = h1buf[1 ^ (d & 1)];
        const bool l1enc = d < SS;
        const bool l0enc = (d + 1) < SS;
        const int  v1    = (d < 47);
        lstm_merged<<<ggrid, 256, 0, stream>>>(
            1, l1enc ? bW[3] : bW[7], h1in, l1enc ? bW[2] : bW[6], h0cur,
            HH, nullptr, b4 + (l1enc ? 1 : 3) * 1024, c1, h1out,
            v1, l0enc ? bW[1] : bW[5], h0cur, l0enc ? bW[0] : bW[4], bemb,
            EE, toks + (size_t)(d + 1 < 48 ? d + 1 : 47) * BB, b4 + (l0enc ? 0 : 2) * 1024, c0, h0nxt);
        if (d >= SS)
            fc_step_kernel<<<512, 256, 0, stream>>>(h1out, bfcW, fcb, out, d - SS);
    }
}